// Round 18
// baseline (449.848 us; speedup 1.0000x reference)
//
#include <hip/hip_runtime.h>
#include <hip/hip_bf16.h>

typedef float f32x4 __attribute__((ext_vector_type(4)));
typedef short s16x8 __attribute__((ext_vector_type(8)));
typedef unsigned short u16;
typedef unsigned short u16x4 __attribute__((ext_vector_type(4)));

#define N_TOK 4096
#define DIM 1024
#define HID 4096
#define NE 8
#define MAXMB 72

#define WAITV(n) asm volatile("s_waitcnt vmcnt(" #n ")" ::: "memory")

__device__ __forceinline__ void wgbar() {
  asm volatile("s_waitcnt lgkmcnt(0)" ::: "memory");
  __builtin_amdgcn_s_barrier();
  asm volatile("" ::: "memory");
}

__device__ __forceinline__ u16 f2bf(float f) {
  unsigned u = __float_as_uint(f);
  u += 0x7fffu + ((u >> 16) & 1u);   // round-to-nearest-even
  return (u16)(u >> 16);
}

__device__ __forceinline__ void gload16(const u16* g, u16* l) {
  __builtin_amdgcn_global_load_lds(
      (const __attribute__((address_space(1))) unsigned int*)g,
      (__attribute__((address_space(3))) unsigned int*)l, 16, 0, 0);
}

// gate + x->bf16; gw rows loaded as 2x float4 (8 contiguous floats per d).
__global__ __launch_bounds__(256) void gate_kernel(
    const float* __restrict__ x, const float* __restrict__ gw,
    const float* __restrict__ gb, int* __restrict__ counts,
    int* __restrict__ tlist, int* __restrict__ eid, int* __restrict__ pos,
    float* __restrict__ wgt, u16* __restrict__ xb) {
  int t = blockIdx.x * 4 + (threadIdx.x >> 6);
  int lane = threadIdx.x & 63;
  float acc[NE];
  #pragma unroll
  for (int e = 0; e < NE; ++e) acc[e] = 0.f;
  const float* xr = x + (size_t)t * DIM;
  u16* xbr = xb + (size_t)t * DIM;
  #pragma unroll
  for (int it = 0; it < DIM / 256; ++it) {
    int d0 = it * 256 + lane * 4;
    float4 v = *(const float4*)&xr[d0];
    u16x4 o = {f2bf(v.x), f2bf(v.y), f2bf(v.z), f2bf(v.w)};
    *(u16x4*)&xbr[d0] = o;
    float xv[4] = {v.x, v.y, v.z, v.w};
    #pragma unroll
    for (int j = 0; j < 4; ++j) {
      const float4* g = (const float4*)(gw + (size_t)(d0 + j) * NE);
      float4 ga = g[0];
      float4 gb4 = g[1];
      acc[0] += xv[j] * ga.x;  acc[1] += xv[j] * ga.y;
      acc[2] += xv[j] * ga.z;  acc[3] += xv[j] * ga.w;
      acc[4] += xv[j] * gb4.x; acc[5] += xv[j] * gb4.y;
      acc[6] += xv[j] * gb4.z; acc[7] += xv[j] * gb4.w;
    }
  }
  #pragma unroll
  for (int off = 32; off > 0; off >>= 1) {
    #pragma unroll
    for (int e = 0; e < NE; ++e) acc[e] += __shfl_down(acc[e], off);
  }
  if (lane == 0) {
    #pragma unroll
    for (int e = 0; e < NE; ++e) acc[e] += gb[e];
    int i0 = 0; float v0 = acc[0];
    #pragma unroll
    for (int e = 1; e < NE; ++e) if (acc[e] > v0) { v0 = acc[e]; i0 = e; }
    int i1 = -1; float v1 = -1e30f;
    #pragma unroll
    for (int e = 0; e < NE; ++e) if (e != i0 && acc[e] > v1) { v1 = acc[e]; i1 = e; }
    float z = expf(v1 - v0);            // v0 >= v1
    float s0 = 1.f / (1.f + z);
    float s1 = z / (1.f + z);
    int p0 = atomicAdd(&counts[i0], 1);
    tlist[i0 * N_TOK + p0] = t * 2 + 0;
    eid[2 * t] = i0; pos[2 * t] = p0; wgt[2 * t] = s0;
    int p1 = atomicAdd(&counts[i1], 1);
    tlist[i1 * N_TOK + p1] = t * 2 + 1;
    eid[2 * t + 1] = i1; pos[2 * t + 1] = p1; wgt[2 * t + 1] = s1;
  }
}

// Builds dense m-block schedule: experts padded to 128-row slot regions.
__global__ void scan_kernel(const int* __restrict__ counts, int* __restrict__ offs,
                            int* __restrict__ poffs, int* __restrict__ nmb,
                            int* __restrict__ mb2e, int* __restrict__ mb2m0) {
  if (threadIdx.x == 0) {
    int s = 0, p = 0, mb = 0;
    for (int e = 0; e < NE; ++e) {
      offs[e] = s; poffs[e] = p;
      int nb = (counts[e] + 127) >> 7;
      for (int i = 0; i < nb; ++i) { mb2e[mb] = e; mb2m0[mb] = i * 128; ++mb; }
      s += counts[e]; p += nb * 128;
    }
    offs[NE] = s; poffs[NE] = p;
    nmb[0] = mb;
    for (int i = mb; i < MAXMB; ++i) { mb2e[i] = 0; mb2m0[i] = 0; }
  }
}

// GEMM1: h[pslot, H] = relu(x[token, D] * w1[e] + b1[e]) -> bf16
// B NATIVE: w1[e][D][H] is k-major; per K-step reg-stage 64x128 fp32 tile,
// convert in reg, write transposed into padded LDS [128][72] (no transpose pass).
// A: xb bf16 via global_load_lds (XOR-swizzled source). 512 thr / 8 waves.
__global__ __launch_bounds__(512) void gemm1_kernel(
    const u16* __restrict__ xb, const float* __restrict__ w1,
    const float* __restrict__ b1, const int* __restrict__ counts,
    const int* __restrict__ poffs, const int* __restrict__ nmb,
    const int* __restrict__ mb2e, const int* __restrict__ mb2m0,
    const int* __restrict__ tlist, u16* __restrict__ hbuf) {
  int mb = blockIdx.y;
  if (mb >= nmb[0]) return;
  int n0 = blockIdx.x << 7;
  int e = mb2e[mb];
  int m0 = mb2m0[mb];
  int ne = counts[e];
  int tid = threadIdx.x;

  // per stage: A[128][64] (8192 u16) + B[128][72] padded (9216 u16) = 17408
  __shared__ u16 lds[34816];

  int srow = tid >> 3;
  int sch  = tid & 7;
  int kch  = ((sch ^ (srow & 7)) * 8);
  const u16* aSrc[2];
  #pragma unroll
  for (int j = 0; j < 2; ++j) {
    int r = m0 + j * 64 + srow;
    int idx = r < ne ? r : ne - 1;
    aSrc[j] = xb + (size_t)(tlist[e * N_TOK + idx] >> 1) * DIM + kch;
  }

  int n2 = (tid & 63) * 2;    // B col pair (0..126)
  int kb = (tid >> 6) * 8;    // B k-group (0..56)
  const float* bS = w1 + (size_t)e * DIM * HID + n0 + n2;   // + k*HID per row

#define STGA(kk, s) do { \
    gload16(aSrc[0] + (kk), &lds[(s) * 17408 + (0 * 64 + srow) * 64 + sch * 8]); \
    gload16(aSrc[1] + (kk), &lds[(s) * 17408 + (1 * 64 + srow) * 64 + sch * 8]); } while (0)
#define LDB(kk) do { _Pragma("unroll") \
    for (int j = 0; j < 8; ++j) bvv[j] = *(const float2*)(bS + (size_t)((kk) + kb + j) * HID); } while (0)
#define WRB(s) do { u16 lo[8], hi[8]; _Pragma("unroll") \
    for (int j = 0; j < 8; ++j) { lo[j] = f2bf(bvv[j].x); hi[j] = f2bf(bvv[j].y); } \
    *(s16x8*)&lds[(s) * 17408 + 8192 + (n2 + 0) * 72 + kb] = *(const s16x8*)lo; \
    *(s16x8*)&lds[(s) * 17408 + 8192 + (n2 + 1) * 72 + kb] = *(const s16x8*)hi; } while (0)

  int lane = tid & 63;
  int wv = tid >> 6;
  int wr = (wv >> 2) * 64;
  int wc = (wv & 3) * 32;
  int fr = lane & 15, fq = lane >> 4;

  f32x4 acc[4][2];
  #pragma unroll
  for (int m = 0; m < 4; ++m)
    #pragma unroll
    for (int n = 0; n < 2; ++n) { f32x4 z = {0.f, 0.f, 0.f, 0.f}; acc[m][n] = z; }

  float2 bvv[8];
  LDB(0);
  STGA(0, 0);
  WRB(0);                      // compiler waits on bvv regs
  for (int t = 0; t < 16; ++t) {
    int cs = t & 1;
    if (t < 15) { LDB((t + 1) * 64); STGA((t + 1) * 64, cs ^ 1); WAITV(10); }
    else        { WAITV(0); }
    wgbar();
    {
      const u16* Ab = &lds[cs * 17408];
      const u16* Bb = &lds[cs * 17408 + 8192];
      __builtin_amdgcn_s_setprio(1);
      #pragma unroll
      for (int th = 0; th < 2; ++th) {
        s16x8 af[4], bf_[2];
        #pragma unroll
        for (int m = 0; m < 4; ++m) {
          int row = wr + m * 16 + fr;
          af[m] = *(const s16x8*)&Ab[row * 64 + (((th * 4 + fq) ^ (row & 7)) * 8)];
        }
        #pragma unroll
        for (int n = 0; n < 2; ++n) {
          int row = wc + n * 16 + fr;
          bf_[n] = *(const s16x8*)&Bb[row * 72 + (th * 4 + fq) * 8];
        }
        #pragma unroll
        for (int m = 0; m < 4; ++m)
          #pragma unroll
          for (int n = 0; n < 2; ++n)
            acc[m][n] = __builtin_amdgcn_mfma_f32_16x16x32_bf16(af[m], bf_[n], acc[m][n], 0, 0, 0);
      }
      __builtin_amdgcn_s_setprio(0);
    }
    if (t < 15) WRB(cs ^ 1);
    wgbar();
  }
#undef STGA
#undef LDB
#undef WRB

  int pbase = poffs[e] + m0;
  float bias[2];
  #pragma unroll
  for (int n = 0; n < 2; ++n) bias[n] = b1[e * HID + n0 + wc + n * 16 + fr];
  #pragma unroll
  for (int m = 0; m < 4; ++m) {
    #pragma unroll
    for (int j = 0; j < 4; ++j) {
      int row = wr + m * 16 + fq * 4 + j;
      if (m0 + row < ne) {
        u16* hr = hbuf + (size_t)(pbase + row) * HID + n0;
        #pragma unroll
        for (int n = 0; n < 2; ++n) {
          int col = wc + n * 16 + fr;
          float v = acc[m][n][j] + bias[n];
          hr[col] = f2bf(fmaxf(v, 0.f));
        }
      }
    }
  }
}

// GEMM2: y[pslot, D] = h[pslot, H] * w2[e] + b2[e] -> fp32
// B NATIVE: w2[e][H][D] is k-major. Same structure; split-K x2 (z in grid.x).
__global__ __launch_bounds__(512) void gemm2_kernel(
    const u16* __restrict__ hbuf, const float* __restrict__ w2,
    const float* __restrict__ b2, const int* __restrict__ counts,
    const int* __restrict__ poffs, const int* __restrict__ nmb,
    const int* __restrict__ mb2e, const int* __restrict__ mb2m0,
    float* __restrict__ yb0, float* __restrict__ yb1) {
  int mb = blockIdx.y;
  if (mb >= nmb[0]) return;
  int z = blockIdx.x >> 3;
  int n0 = (blockIdx.x & 7) << 7;
  int e = mb2e[mb];
  int m0 = mb2m0[mb];
  int ne = counts[e];
  int kz = z * (HID / 2);
  int tid = threadIdx.x;
  int pbase = poffs[e] + m0;

  __shared__ u16 lds[34816];

  int srow = tid >> 3;
  int sch  = tid & 7;
  int kch  = ((sch ^ (srow & 7)) * 8);
  const u16* aSrc[2];
  #pragma unroll
  for (int j = 0; j < 2; ++j) {
    int r = m0 + j * 64 + srow;
    int idx = r < ne ? r : ne - 1;
    aSrc[j] = hbuf + (size_t)(poffs[e] + idx) * HID + kz + kch;
  }

  int n2 = (tid & 63) * 2;
  int kb = (tid >> 6) * 8;
  const float* bS = w2 + ((size_t)e * HID + kz) * DIM + n0 + n2;   // + k*DIM per row

#define STGA(kk, s) do { \
    gload16(aSrc[0] + (kk), &lds[(s) * 17408 + (0 * 64 + srow) * 64 + sch * 8]); \
    gload16(aSrc[1] + (kk), &lds[(s) * 17408 + (1 * 64 + srow) * 64 + sch * 8]); } while (0)
#define LDB(kk) do { _Pragma("unroll") \
    for (int j = 0; j < 8; ++j) bvv[j] = *(const float2*)(bS + (size_t)((kk) + kb + j) * DIM); } while (0)
#define WRB(s) do { u16 lo[8], hi[8]; _Pragma("unroll") \
    for (int j = 0; j < 8; ++j) { lo[j] = f2bf(bvv[j].x); hi[j] = f2bf(bvv[j].y); } \
    *(s16x8*)&lds[(s) * 17408 + 8192 + (n2 + 0) * 72 + kb] = *(const s16x8*)lo; \
    *(s16x8*)&lds[(s) * 17408 + 8192 + (n2 + 1) * 72 + kb] = *(const s16x8*)hi; } while (0)

  int lane = tid & 63;
  int wv = tid >> 6;
  int wr = (wv >> 2) * 64;
  int wc = (wv & 3) * 32;
  int fr = lane & 15, fq = lane >> 4;

  f32x4 acc[4][2];
  #pragma unroll
  for (int m = 0; m < 4; ++m)
    #pragma unroll
    for (int n = 0; n < 2; ++n) { f32x4 zz = {0.f, 0.f, 0.f, 0.f}; acc[m][n] = zz; }

  float2 bvv[8];
  LDB(0);
  STGA(0, 0);
  WRB(0);
  for (int t = 0; t < 32; ++t) {
    int cs = t & 1;
    if (t < 31) { LDB((t + 1) * 64); STGA((t + 1) * 64, cs ^ 1); WAITV(10); }
    else        { WAITV(0); }
    wgbar();
    {
      const u16* Ab = &lds[cs * 17408];
      const u16* Bb = &lds[cs * 17408 + 8192];
      __builtin_amdgcn_s_setprio(1);
      #pragma unroll
      for (int th = 0; th < 2; ++th) {
        s16x8 af[4], bf_[2];
        #pragma unroll
        for (int m = 0; m < 4; ++m) {
          int row = wr + m * 16 + fr;
          af[m] = *(const s16x8*)&Ab[row * 64 + (((th * 4 + fq) ^ (row & 7)) * 8)];
        }
        #pragma unroll
        for (int n = 0; n < 2; ++n) {
          int row = wc + n * 16 + fr;
          bf_[n] = *(const s16x8*)&Bb[row * 72 + (th * 4 + fq) * 8];
        }
        #pragma unroll
        for (int m = 0; m < 4; ++m)
          #pragma unroll
          for (int n = 0; n < 2; ++n)
            acc[m][n] = __builtin_amdgcn_mfma_f32_16x16x32_bf16(af[m], bf_[n], acc[m][n], 0, 0, 0);
      }
      __builtin_amdgcn_s_setprio(0);
    }
    if (t < 31) WRB(cs ^ 1);
    wgbar();
  }
#undef STGA
#undef LDB
#undef WRB

  float* yb = z ? yb1 : yb0;
  float bias[2];
  #pragma unroll
  for (int n = 0; n < 2; ++n)
    bias[n] = (z == 0) ? b2[e * DIM + n0 + wc + n * 16 + fr] : 0.f;
  #pragma unroll
  for (int m = 0; m < 4; ++m) {
    #pragma unroll
    for (int j = 0; j < 4; ++j) {
      int row = wr + m * 16 + fq * 4 + j;
      if (m0 + row < ne) {
        float* yr = yb + (size_t)(pbase + row) * DIM + n0;
        #pragma unroll
        for (int n = 0; n < 2; ++n) {
          int col = wc + n * 16 + fr;
          yr[col] = acc[m][n][j] + bias[n];
        }
      }
    }
  }
}

__global__ __launch_bounds__(256) void combine_kernel(
    const int* __restrict__ eid, const int* __restrict__ pos,
    const float* __restrict__ wgt, const int* __restrict__ poffs,
    const float* __restrict__ yb0, const float* __restrict__ yb1,
    float* __restrict__ out) {
  int t = blockIdx.x;
  int e0 = eid[2 * t], e1 = eid[2 * t + 1];
  float w0 = wgt[2 * t], w1v = wgt[2 * t + 1];
  size_t g0 = (size_t)(poffs[e0] + pos[2 * t]) * DIM;
  size_t g1 = (size_t)(poffs[e1] + pos[2 * t + 1]) * DIM;
  int d = threadIdx.x * 4;
  float4 a0 = *(const float4*)&yb0[g0 + d];
  float4 a1 = *(const float4*)&yb1[g0 + d];
  float4 b0 = *(const float4*)&yb0[g1 + d];
  float4 b1v = *(const float4*)&yb1[g1 + d];
  float4 o;
  o.x = w0 * (a0.x + a1.x) + w1v * (b0.x + b1v.x);
  o.y = w0 * (a0.y + a1.y) + w1v * (b0.y + b1v.y);
  o.z = w0 * (a0.z + a1.z) + w1v * (b0.z + b1v.z);
  o.w = w0 * (a0.w + a1.w) + w1v * (b0.w + b1v.w);
  *(float4*)&out[(size_t)t * DIM + d] = o;
}

extern "C" void kernel_launch(void* const* d_in, const int* in_sizes, int n_in,
                              void* d_out, int out_size, void* d_ws, size_t ws_size,
                              hipStream_t stream) {
  const float* x  = (const float*)d_in[0];
  const float* gw = (const float*)d_in[1];
  const float* gb = (const float*)d_in[2];
  const float* w1 = (const float*)d_in[3];
  const float* b1 = (const float*)d_in[4];
  const float* w2 = (const float*)d_in[5];
  const float* b2 = (const float*)d_in[6];
  float* out = (float*)d_out;

  char* ws = (char*)d_ws;
  const size_t MB = 1ull << 20;
  // layout: [0,8) xb | [8,80) hbuf | [80,116) yb0 | [116,152) yb1 | meta @152
  u16*   xb     = (u16*)(ws);
  u16*   hbuf   = (u16*)(ws + 8 * MB);
  float* yb0    = (float*)(ws + 80 * MB);
  float* yb1    = (float*)(ws + 116 * MB);
  char*  meta   = ws + 152 * MB;
  int*   eid    = (int*)(meta);
  int*   pos    = (int*)(meta + 32 * 1024);
  float* wgt    = (float*)(meta + 64 * 1024);
  int*   counts = (int*)(meta + 96 * 1024);
  int*   offs   = (int*)(meta + 96 * 1024 + 256);
  int*   poffs  = (int*)(meta + 96 * 1024 + 512);
  int*   nmb    = (int*)(meta + 96 * 1024 + 768);
  int*   mb2e   = (int*)(meta + 96 * 1024 + 1024);
  int*   mb2m0  = (int*)(meta + 96 * 1024 + 2048);
  int*   tlist  = (int*)(meta + 128 * 1024);

  hipMemsetAsync(counts, 0, NE * sizeof(int), stream);
  gate_kernel<<<N_TOK / 4, 256, 0, stream>>>(x, gw, gb, counts, tlist, eid, pos, wgt, xb);
  scan_kernel<<<1, 64, 0, stream>>>(counts, offs, poffs, nmb, mb2e, mb2m0);
  gemm1_kernel<<<dim3(32, MAXMB), 512, 0, stream>>>(xb, w1, b1, counts, poffs, nmb, mb2e, mb2m0, tlist, hbuf);
  gemm2_kernel<<<dim3(16, MAXMB), 512, 0, stream>>>(hbuf, w2, b2, counts, poffs, nmb, mb2e, mb2m0, yb0, yb1);
  combine_kernel<<<N_TOK, 256, 0, stream>>>(eid, pos, wgt, poffs, yb0, yb1, out);
}

// Round 20
// 409.492 us; speedup vs baseline: 1.0986x; 1.0986x over previous
//
#include <hip/hip_runtime.h>
#include <hip/hip_bf16.h>

typedef float f32x4 __attribute__((ext_vector_type(4)));
typedef short s16x8 __attribute__((ext_vector_type(8)));
typedef unsigned short u16;
typedef unsigned short u16x4 __attribute__((ext_vector_type(4)));

#define N_TOK 4096
#define DIM 1024
#define HID 4096
#define NE 8
#define MAXMB 72

#define WAITV(n) asm volatile("s_waitcnt vmcnt(" #n ")" ::: "memory")

__device__ __forceinline__ void wgbar() {
  asm volatile("" ::: "memory");
  __builtin_amdgcn_s_barrier();
  asm volatile("" ::: "memory");
}

__device__ __forceinline__ u16 f2bf(float f) {
  unsigned u = __float_as_uint(f);
  u += 0x7fffu + ((u >> 16) & 1u);   // round-to-nearest-even
  return (u16)(u >> 16);
}

__device__ __forceinline__ void gload16(const u16* g, u16* l) {
  __builtin_amdgcn_global_load_lds(
      (const __attribute__((address_space(1))) unsigned int*)g,
      (__attribute__((address_space(3))) unsigned int*)l, 16, 0, 0);
}

// gate + x->bf16; gw rows loaded as 2x float4 (8 contiguous floats per d).
__global__ __launch_bounds__(256) void gate_kernel(
    const float* __restrict__ x, const float* __restrict__ gw,
    const float* __restrict__ gb, int* __restrict__ counts,
    int* __restrict__ tlist, int* __restrict__ eid, int* __restrict__ pos,
    float* __restrict__ wgt, u16* __restrict__ xb) {
  int t = blockIdx.x * 4 + (threadIdx.x >> 6);
  int lane = threadIdx.x & 63;
  float acc[NE];
  #pragma unroll
  for (int e = 0; e < NE; ++e) acc[e] = 0.f;
  const float* xr = x + (size_t)t * DIM;
  u16* xbr = xb + (size_t)t * DIM;
  #pragma unroll
  for (int it = 0; it < DIM / 256; ++it) {
    int d0 = it * 256 + lane * 4;
    float4 v = *(const float4*)&xr[d0];
    u16x4 o = {f2bf(v.x), f2bf(v.y), f2bf(v.z), f2bf(v.w)};
    *(u16x4*)&xbr[d0] = o;
    float xv[4] = {v.x, v.y, v.z, v.w};
    #pragma unroll
    for (int j = 0; j < 4; ++j) {
      const float4* g = (const float4*)(gw + (size_t)(d0 + j) * NE);
      float4 ga = g[0];
      float4 gb4 = g[1];
      acc[0] += xv[j] * ga.x;  acc[1] += xv[j] * ga.y;
      acc[2] += xv[j] * ga.z;  acc[3] += xv[j] * ga.w;
      acc[4] += xv[j] * gb4.x; acc[5] += xv[j] * gb4.y;
      acc[6] += xv[j] * gb4.z; acc[7] += xv[j] * gb4.w;
    }
  }
  #pragma unroll
  for (int off = 32; off > 0; off >>= 1) {
    #pragma unroll
    for (int e = 0; e < NE; ++e) acc[e] += __shfl_down(acc[e], off);
  }
  if (lane == 0) {
    #pragma unroll
    for (int e = 0; e < NE; ++e) acc[e] += gb[e];
    int i0 = 0; float v0 = acc[0];
    #pragma unroll
    for (int e = 1; e < NE; ++e) if (acc[e] > v0) { v0 = acc[e]; i0 = e; }
    int i1 = -1; float v1 = -1e30f;
    #pragma unroll
    for (int e = 0; e < NE; ++e) if (e != i0 && acc[e] > v1) { v1 = acc[e]; i1 = e; }
    float z = expf(v1 - v0);            // v0 >= v1
    float s0 = 1.f / (1.f + z);
    float s1 = z / (1.f + z);
    int p0 = atomicAdd(&counts[i0], 1);
    tlist[i0 * N_TOK + p0] = t * 2 + 0;
    eid[2 * t] = i0; pos[2 * t] = p0; wgt[2 * t] = s0;
    int p1 = atomicAdd(&counts[i1], 1);
    tlist[i1 * N_TOK + p1] = t * 2 + 1;
    eid[2 * t + 1] = i1; pos[2 * t + 1] = p1; wgt[2 * t + 1] = s1;
  }
}

// Builds dense m-block schedule: experts padded to 128-row slot regions.
__global__ void scan_kernel(const int* __restrict__ counts, int* __restrict__ offs,
                            int* __restrict__ poffs, int* __restrict__ nmb,
                            int* __restrict__ mb2e, int* __restrict__ mb2m0) {
  if (threadIdx.x == 0) {
    int s = 0, p = 0, mb = 0;
    for (int e = 0; e < NE; ++e) {
      offs[e] = s; poffs[e] = p;
      int nb = (counts[e] + 127) >> 7;
      for (int i = 0; i < nb; ++i) { mb2e[mb] = e; mb2m0[mb] = i * 128; ++mb; }
      s += counts[e]; p += nb * 128;
    }
    offs[NE] = s; poffs[NE] = p;
    nmb[0] = mb;
    for (int i = mb; i < MAXMB; ++i) { mb2e[i] = 0; mb2m0[i] = 0; }
  }
}

// w1[e][D][H] -> w1t[e][H][D] transpose (64x64 tiles), standalone.
__global__ __launch_bounds__(256) void w1trans_kernel(
    const float* __restrict__ w1, u16* __restrict__ w1t) {
  __shared__ u16 tile[64][65];
  int bid = blockIdx.x;
  int e = bid >> 10;
  int rem = bid & 1023;
  int rt = rem >> 6, ct = rem & 63;
  int r0 = rt * 64, c0 = ct * 64;
  int tid = threadIdx.x;
  int rr = tid >> 4;          // 0..15
  int cc = (tid & 15) * 4;    // 0..60
  const float* src = w1 + (size_t)e * DIM * HID + (size_t)r0 * HID + c0;
  #pragma unroll
  for (int rd = 0; rd < 4; ++rd) {
    int r = rd * 16 + rr;
    float4 v = *(const float4*)&src[(size_t)r * HID + cc];
    tile[r][cc + 0] = f2bf(v.x);
    tile[r][cc + 1] = f2bf(v.y);
    tile[r][cc + 2] = f2bf(v.z);
    tile[r][cc + 3] = f2bf(v.w);
  }
  __syncthreads();
  u16* dst = w1t + (size_t)e * DIM * HID + (size_t)c0 * DIM + r0;
  int oc2 = tid >> 3;          // 0..31
  int cc8 = (tid & 7) * 8;     // 0..56
  #pragma unroll
  for (int rd = 0; rd < 2; ++rd) {
    int oc = rd * 32 + oc2;
    u16 tmp[8];
    #pragma unroll
    for (int jj = 0; jj < 8; ++jj) tmp[jj] = tile[cc8 + jj][oc];
    *(s16x8*)&dst[(size_t)oc * DIM + cc8] = *(const s16x8*)tmp;
  }
}

// fused2: blocks [0,2304) = GEMM1 (128x128, BK=32, ring-3, TWO barriers/step
//         [R8-verified sync], 8 waves, 48KB LDS -> 3 blk/CU = 24 waves/CU);
//         blocks [2304,6400) = w2 transpose (two 64x64 tiles per block).
__global__ __launch_bounds__(512) void fused2_kernel(
    const u16* __restrict__ xb, const u16* __restrict__ w1t,
    const float* __restrict__ b1, const int* __restrict__ counts,
    const int* __restrict__ poffs, const int* __restrict__ nmb,
    const int* __restrict__ mb2e, const int* __restrict__ mb2m0,
    const int* __restrict__ tlist, u16* __restrict__ hbuf,
    const float* __restrict__ w2, u16* __restrict__ w2t) {
  int bid = blockIdx.x;
  int tid = threadIdx.x;
  __shared__ u16 lds[24576];   // gemm: 3 stages x (A 4096 | B 4096) u16 = 48KB

  if (bid >= 2304) {
    // ---- w2 transpose: two 64x64 tiles ----
    int half = tid >> 8;          // 0/1
    int htid = tid & 255;
    int tileIdx = (bid - 2304) * 2 + half;
    int e = tileIdx >> 10;
    int rem = tileIdx & 1023;
    int rt = rem >> 4, ct = rem & 15;   // R=4096 (64 r-tiles), C=1024 (16 c-tiles)
    int r0 = rt * 64, c0 = ct * 64;
    u16* tile = &lds[half * 4160];      // [64][65] scalar-indexed
    int rr = htid >> 4;
    int cc = (htid & 15) * 4;
    const float* src = w2 + (size_t)e * HID * DIM + (size_t)r0 * DIM + c0;
    #pragma unroll
    for (int rd = 0; rd < 4; ++rd) {
      int r = rd * 16 + rr;
      float4 v = *(const float4*)&src[(size_t)r * DIM + cc];
      tile[r * 65 + cc + 0] = f2bf(v.x);
      tile[r * 65 + cc + 1] = f2bf(v.y);
      tile[r * 65 + cc + 2] = f2bf(v.z);
      tile[r * 65 + cc + 3] = f2bf(v.w);
    }
    __syncthreads();
    u16* dst = w2t + (size_t)e * HID * DIM + (size_t)c0 * HID + r0;
    int oc2 = htid >> 3;
    int cc8 = (htid & 7) * 8;
    #pragma unroll
    for (int rd = 0; rd < 2; ++rd) {
      int oc = rd * 32 + oc2;
      u16 tmp[8];
      #pragma unroll
      for (int jj = 0; jj < 8; ++jj) tmp[jj] = tile[(cc8 + jj) * 65 + oc];
      *(s16x8*)&dst[(size_t)oc * HID + cc8] = *(const s16x8*)tmp;
    }
    return;
  }

  // ---- GEMM1: h = relu(xb * w1t^T + b1) -> bf16 ----
  int mb = bid >> 5;
  if (mb >= nmb[0]) return;
  int n0 = (bid & 31) << 7;
  int e = mb2e[mb];
  int m0 = mb2m0[mb];
  int ne = counts[e];

  int arow = tid >> 2;                  // 0..127
  int asl  = tid & 3;
  int akch = ((asl ^ (arow & 3)) * 8);  // pre-swizzled source chunk (4-slot XOR)
  const u16* aS;
  {
    int r = m0 + arow;
    int idx = r < ne ? r : ne - 1;
    aS = xb + (size_t)(tlist[e * N_TOK + idx] >> 1) * DIM + akch;
  }
  const u16* bS = w1t + ((size_t)e * HID + n0 + arow) * DIM + akch;

#define STG(kk, s) do { \
    gload16(aS + (kk), &lds[(s) * 8192 + tid * 8]); \
    gload16(bS + (kk), &lds[(s) * 8192 + 4096 + tid * 8]); } while (0)

  int lane = tid & 63;
  int wv = tid >> 6;
  int wr = (wv >> 2) * 64;
  int wc = (wv & 3) * 32;
  int fr = lane & 15, fq = lane >> 4;

  f32x4 acc[4][2];
  #pragma unroll
  for (int m = 0; m < 4; ++m)
    #pragma unroll
    for (int n = 0; n < 2; ++n) { f32x4 z = {0.f, 0.f, 0.f, 0.f}; acc[m][n] = z; }

  STG(0, 0);
  STG(32, 1);
  int s0 = 0, s1 = 1, s2 = 2;
  for (int t = 0; t < 32; ++t) {
    if (t < 30)       { STG((t + 2) * 32, s2); WAITV(4); }
    else if (t == 30) { WAITV(2); }
    else              { WAITV(0); }
    wgbar();                         // stage(t) ready for all waves
    {
      const u16* Ab = &lds[s0 * 8192];
      const u16* Bb = &lds[s0 * 8192 + 4096];
      __builtin_amdgcn_s_setprio(1);
      s16x8 af[4], bf_[2];
      #pragma unroll
      for (int m = 0; m < 4; ++m) {
        int row = wr + m * 16 + fr;
        af[m] = *(const s16x8*)&Ab[row * 32 + ((fq ^ (row & 3)) * 8)];
      }
      #pragma unroll
      for (int n = 0; n < 2; ++n) {
        int row = wc + n * 16 + fr;
        bf_[n] = *(const s16x8*)&Bb[row * 32 + ((fq ^ (row & 3)) * 8)];
      }
      #pragma unroll
      for (int m = 0; m < 4; ++m)
        #pragma unroll
        for (int n = 0; n < 2; ++n)
          acc[m][n] = __builtin_amdgcn_mfma_f32_16x16x32_bf16(af[m], bf_[n], acc[m][n], 0, 0, 0);
      __builtin_amdgcn_s_setprio(0);
    }
    wgbar();                         // all waves done reading s0 before it is restaged
    int tmp = s0; s0 = s1; s1 = s2; s2 = tmp;
  }
#undef STG

  int pbase = poffs[e] + m0;
  float bias[2];
  #pragma unroll
  for (int n = 0; n < 2; ++n) bias[n] = b1[e * HID + n0 + wc + n * 16 + fr];
  #pragma unroll
  for (int m = 0; m < 4; ++m) {
    #pragma unroll
    for (int j = 0; j < 4; ++j) {
      int row = wr + m * 16 + fq * 4 + j;
      if (m0 + row < ne) {
        u16* hr = hbuf + (size_t)(pbase + row) * HID + n0;
        #pragma unroll
        for (int n = 0; n < 2; ++n) {
          int col = wc + n * 16 + fr;
          float v = acc[m][n][j] + bias[n];
          hr[col] = f2bf(fmaxf(v, 0.f));
        }
      }
    }
  }
}

// GEMM2: y[pslot, D] = h[pslot, H] * w2t[e]^T + b2[e] -> fp32
// 128x128, BK=32, ring-3, TWO barriers/step, split-K x2, 48KB LDS.
__global__ __launch_bounds__(512) void gemm2_kernel(
    const u16* __restrict__ hbuf, const u16* __restrict__ w2t,
    const float* __restrict__ b2, const int* __restrict__ counts,
    const int* __restrict__ poffs, const int* __restrict__ nmb,
    const int* __restrict__ mb2e, const int* __restrict__ mb2m0,
    float* __restrict__ yb0, float* __restrict__ yb1) {
  int mb = blockIdx.y;
  if (mb >= nmb[0]) return;
  int n0 = blockIdx.x << 7;
  int z = blockIdx.z;
  int e = mb2e[mb];
  int m0 = mb2m0[mb];
  int ne = counts[e];
  int kz = z * (HID / 2);
  int tid = threadIdx.x;
  int pbase = poffs[e] + m0;

  __shared__ u16 lds[24576];

  int arow = tid >> 2;
  int asl  = tid & 3;
  int akch = ((asl ^ (arow & 3)) * 8);
  const u16* aS;
  {
    int r = m0 + arow;
    int idx = r < ne ? r : ne - 1;
    aS = hbuf + (size_t)(poffs[e] + idx) * HID + kz + akch;
  }
  const u16* bS = w2t + ((size_t)e * DIM + n0 + arow) * HID + kz + akch;

#define STG(kk, s) do { \
    gload16(aS + (kk), &lds[(s) * 8192 + tid * 8]); \
    gload16(bS + (kk), &lds[(s) * 8192 + 4096 + tid * 8]); } while (0)

  int lane = tid & 63;
  int wv = tid >> 6;
  int wr = (wv >> 2) * 64;
  int wc = (wv & 3) * 32;
  int fr = lane & 15, fq = lane >> 4;

  f32x4 acc[4][2];
  #pragma unroll
  for (int m = 0; m < 4; ++m)
    #pragma unroll
    for (int n = 0; n < 2; ++n) { f32x4 zz = {0.f, 0.f, 0.f, 0.f}; acc[m][n] = zz; }

  STG(0, 0);
  STG(32, 1);
  int s0 = 0, s1 = 1, s2 = 2;
  for (int t = 0; t < 64; ++t) {
    if (t < 62)       { STG((t + 2) * 32, s2); WAITV(4); }
    else if (t == 62) { WAITV(2); }
    else              { WAITV(0); }
    wgbar();
    {
      const u16* Ab = &lds[s0 * 8192];
      const u16* Bb = &lds[s0 * 8192 + 4096];
      __builtin_amdgcn_s_setprio(1);
      s16x8 af[4], bf_[2];
      #pragma unroll
      for (int m = 0; m < 4; ++m) {
        int row = wr + m * 16 + fr;
        af[m] = *(const s16x8*)&Ab[row * 32 + ((fq ^ (row & 3)) * 8)];
      }
      #pragma unroll
      for (int n = 0; n < 2; ++n) {
        int row = wc + n * 16 + fr;
        bf_[n] = *(const s16x8*)&Bb[row * 32 + ((fq ^ (row & 3)) * 8)];
      }
      #pragma unroll
      for (int m = 0; m < 4; ++m)
        #pragma unroll
        for (int n = 0; n < 2; ++n)
          acc[m][n] = __builtin_amdgcn_mfma_f32_16x16x32_bf16(af[m], bf_[n], acc[m][n], 0, 0, 0);
      __builtin_amdgcn_s_setprio(0);
    }
    wgbar();
    int tmp = s0; s0 = s1; s1 = s2; s2 = tmp;
  }
#undef STG

  float* yb = z ? yb1 : yb0;
  float bias[2];
  #pragma unroll
  for (int n = 0; n < 2; ++n)
    bias[n] = (z == 0) ? b2[e * DIM + n0 + wc + n * 16 + fr] : 0.f;
  #pragma unroll
  for (int m = 0; m < 4; ++m) {
    #pragma unroll
    for (int j = 0; j < 4; ++j) {
      int row = wr + m * 16 + fq * 4 + j;
      if (m0 + row < ne) {
        float* yr = yb + (size_t)(pbase + row) * DIM + n0;
        #pragma unroll
        for (int n = 0; n < 2; ++n) {
          int col = wc + n * 16 + fr;
          yr[col] = acc[m][n][j] + bias[n];
        }
      }
    }
  }
}

__global__ __launch_bounds__(256) void combine_kernel(
    const int* __restrict__ eid, const int* __restrict__ pos,
    const float* __restrict__ wgt, const int* __restrict__ poffs,
    const float* __restrict__ yb0, const float* __restrict__ yb1,
    float* __restrict__ out) {
  int t = blockIdx.x;
  int e0 = eid[2 * t], e1 = eid[2 * t + 1];
  float w0 = wgt[2 * t], w1v = wgt[2 * t + 1];
  size_t g0 = (size_t)(poffs[e0] + pos[2 * t]) * DIM;
  size_t g1 = (size_t)(poffs[e1] + pos[2 * t + 1]) * DIM;
  int d = threadIdx.x * 4;
  float4 a0 = *(const float4*)&yb0[g0 + d];
  float4 a1 = *(const float4*)&yb1[g0 + d];
  float4 b0 = *(const float4*)&yb0[g1 + d];
  float4 b1v = *(const float4*)&yb1[g1 + d];
  float4 o;
  o.x = w0 * (a0.x + a1.x) + w1v * (b0.x + b1v.x);
  o.y = w0 * (a0.y + a1.y) + w1v * (b0.y + b1v.y);
  o.z = w0 * (a0.z + a1.z) + w1v * (b0.z + b1v.z);
  o.w = w0 * (a0.w + a1.w) + w1v * (b0.w + b1v.w);
  *(float4*)&out[(size_t)t * DIM + d] = o;
}

extern "C" void kernel_launch(void* const* d_in, const int* in_sizes, int n_in,
                              void* d_out, int out_size, void* d_ws, size_t ws_size,
                              hipStream_t stream) {
  const float* x  = (const float*)d_in[0];
  const float* gw = (const float*)d_in[1];
  const float* gb = (const float*)d_in[2];
  const float* w1 = (const float*)d_in[3];
  const float* b1 = (const float*)d_in[4];
  const float* w2 = (const float*)d_in[5];
  const float* b2 = (const float*)d_in[6];
  float* out = (float*)d_out;

  char* ws = (char*)d_ws;
  const size_t MB = 1ull << 20;
  // layout: [0,64)   w1t (dead after fused2; yb0 36MB aliases here)
  //         [64,128) w2t
  //         [128,136) xb
  //         [136,208) hbuf
  //         [208,244) yb1
  //         [244,...) meta
  u16*   w1t    = (u16*)(ws);
  float* yb0    = (float*)(ws);              // aliases w1t (dead before gemm2)
  u16*   w2t    = (u16*)(ws + 64 * MB);
  u16*   xb     = (u16*)(ws + 128 * MB);
  u16*   hbuf   = (u16*)(ws + 136 * MB);
  float* yb1    = (float*)(ws + 208 * MB);
  char*  meta   = ws + 244 * MB;
  int*   eid    = (int*)(meta);
  int*   pos    = (int*)(meta + 32 * 1024);
  float* wgt    = (float*)(meta + 64 * 1024);
  int*   counts = (int*)(meta + 96 * 1024);
  int*   offs   = (int*)(meta + 96 * 1024 + 256);
  int*   poffs  = (int*)(meta + 96 * 1024 + 512);
  int*   nmb    = (int*)(meta + 96 * 1024 + 768);
  int*   mb2e   = (int*)(meta + 96 * 1024 + 1024);
  int*   mb2m0  = (int*)(meta + 96 * 1024 + 2048);
  int*   tlist  = (int*)(meta + 128 * 1024);

  hipMemsetAsync(counts, 0, NE * sizeof(int), stream);
  gate_kernel<<<N_TOK / 4, 256, 0, stream>>>(x, gw, gb, counts, tlist, eid, pos, wgt, xb);
  scan_kernel<<<1, 64, 0, stream>>>(counts, offs, poffs, nmb, mb2e, mb2m0);
  w1trans_kernel<<<8192, 256, 0, stream>>>(w1, w1t);
  fused2_kernel<<<6400, 512, 0, stream>>>(xb, w1t, b1, counts, poffs, nmb,
                                          mb2e, mb2m0, tlist, hbuf, w2, w2t);
  gemm2_kernel<<<dim3(8, MAXMB, 2), 512, 0, stream>>>(hbuf, w2t, b2, counts, poffs, nmb, mb2e, mb2m0, yb0, yb1);
  combine_kernel<<<N_TOK, 256, 0, stream>>>(eid, pos, wgt, poffs, yb0, yb1, out);
}

// Round 21
// 377.496 us; speedup vs baseline: 1.1917x; 1.0848x over previous
//
#include <hip/hip_runtime.h>
#include <hip/hip_bf16.h>

typedef float f32x4 __attribute__((ext_vector_type(4)));
typedef short s16x8 __attribute__((ext_vector_type(8)));
typedef unsigned short u16;
typedef unsigned short u16x4 __attribute__((ext_vector_type(4)));

#define N_TOK 4096
#define DIM 1024
#define HID 4096
#define NE 8
#define MAXMB 72

#define WAITV(n) asm volatile("s_waitcnt vmcnt(" #n ")" ::: "memory")

__device__ __forceinline__ void wgbar() {
  asm volatile("" ::: "memory");
  __builtin_amdgcn_s_barrier();
  asm volatile("" ::: "memory");
}

__device__ __forceinline__ u16 f2bf(float f) {
  unsigned u = __float_as_uint(f);
  u += 0x7fffu + ((u >> 16) & 1u);   // round-to-nearest-even
  return (u16)(u >> 16);
}

__device__ __forceinline__ void gload16(const u16* g, u16* l) {
  __builtin_amdgcn_global_load_lds(
      (const __attribute__((address_space(1))) unsigned int*)g,
      (__attribute__((address_space(3))) unsigned int*)l, 16, 0, 0);
}

// fused1: blocks [0,1024) = gate + x->bf16 (FIRST: co-starts with transpose
//         flood, latency hides under it; no serial tail);
//         blocks [1024,9216) = w1[e][D][H] -> w1t[e][H][D] transpose.
__global__ __launch_bounds__(256) void fused1_kernel(
    const float* __restrict__ x, const float* __restrict__ gw,
    const float* __restrict__ gb, const float* __restrict__ w1,
    u16* __restrict__ w1t, int* __restrict__ counts, int* __restrict__ tlist,
    int* __restrict__ eid, int* __restrict__ pos, float* __restrict__ wgt,
    u16* __restrict__ xb) {
  int bid = blockIdx.x;
  int tid = threadIdx.x;
  if (bid >= 1024) {
    __shared__ u16 tile[64][65];
    int tb = bid - 1024;
    int e = tb >> 10;
    int rem = tb & 1023;
    int rt = rem >> 6, ct = rem & 63;
    int r0 = rt * 64, c0 = ct * 64;
    int rr = tid >> 4;          // 0..15
    int cc = (tid & 15) * 4;    // 0..60
    const float* src = w1 + (size_t)e * DIM * HID + (size_t)r0 * HID + c0;
    #pragma unroll
    for (int rd = 0; rd < 4; ++rd) {
      int r = rd * 16 + rr;
      float4 v = *(const float4*)&src[(size_t)r * HID + cc];
      tile[r][cc + 0] = f2bf(v.x);
      tile[r][cc + 1] = f2bf(v.y);
      tile[r][cc + 2] = f2bf(v.z);
      tile[r][cc + 3] = f2bf(v.w);
    }
    __syncthreads();
    u16* dst = w1t + (size_t)e * DIM * HID + (size_t)c0 * DIM + r0;
    int oc2 = tid >> 3;          // 0..31
    int cc8 = (tid & 7) * 8;     // 0..56
    #pragma unroll
    for (int rd = 0; rd < 2; ++rd) {
      int oc = rd * 32 + oc2;
      u16 tmp[8];
      #pragma unroll
      for (int jj = 0; jj < 8; ++jj) tmp[jj] = tile[cc8 + jj][oc];
      *(s16x8*)&dst[(size_t)oc * DIM + cc8] = *(const s16x8*)tmp;
    }
  } else {
    int t = bid * 4 + (tid >> 6);
    int lane = tid & 63;
    float acc[NE];
    #pragma unroll
    for (int e = 0; e < NE; ++e) acc[e] = 0.f;
    const float* xr = x + (size_t)t * DIM;
    u16* xbr = xb + (size_t)t * DIM;
    #pragma unroll
    for (int it = 0; it < DIM / 256; ++it) {
      int d0 = it * 256 + lane * 4;
      float4 v = *(const float4*)&xr[d0];
      u16x4 o = {f2bf(v.x), f2bf(v.y), f2bf(v.z), f2bf(v.w)};
      *(u16x4*)&xbr[d0] = o;
      float xv[4] = {v.x, v.y, v.z, v.w};
      #pragma unroll
      for (int j = 0; j < 4; ++j) {
        const float4* g = (const float4*)(gw + (size_t)(d0 + j) * NE);
        float4 ga = g[0];
        float4 gb4 = g[1];
        acc[0] += xv[j] * ga.x;  acc[1] += xv[j] * ga.y;
        acc[2] += xv[j] * ga.z;  acc[3] += xv[j] * ga.w;
        acc[4] += xv[j] * gb4.x; acc[5] += xv[j] * gb4.y;
        acc[6] += xv[j] * gb4.z; acc[7] += xv[j] * gb4.w;
      }
    }
    #pragma unroll
    for (int off = 32; off > 0; off >>= 1) {
      #pragma unroll
      for (int e = 0; e < NE; ++e) acc[e] += __shfl_down(acc[e], off);
    }
    if (lane == 0) {
      #pragma unroll
      for (int e = 0; e < NE; ++e) acc[e] += gb[e];
      int i0 = 0; float v0 = acc[0];
      #pragma unroll
      for (int e = 1; e < NE; ++e) if (acc[e] > v0) { v0 = acc[e]; i0 = e; }
      int i1 = -1; float v1 = -1e30f;
      #pragma unroll
      for (int e = 0; e < NE; ++e) if (e != i0 && acc[e] > v1) { v1 = acc[e]; i1 = e; }
      float z = expf(v1 - v0);            // v0 >= v1
      float s0 = 1.f / (1.f + z);
      float s1 = z / (1.f + z);
      int p0 = atomicAdd(&counts[i0], 1);
      tlist[i0 * N_TOK + p0] = t * 2 + 0;
      eid[2 * t] = i0; pos[2 * t] = p0; wgt[2 * t] = s0;
      int p1 = atomicAdd(&counts[i1], 1);
      tlist[i1 * N_TOK + p1] = t * 2 + 1;
      eid[2 * t + 1] = i1; pos[2 * t + 1] = p1; wgt[2 * t + 1] = s1;
    }
  }
}

// Builds dense m-block schedule: experts padded to 128-row slot regions.
__global__ void scan_kernel(const int* __restrict__ counts, int* __restrict__ offs,
                            int* __restrict__ poffs, int* __restrict__ nmb,
                            int* __restrict__ mb2e, int* __restrict__ mb2m0) {
  if (threadIdx.x == 0) {
    int s = 0, p = 0, mb = 0;
    for (int e = 0; e < NE; ++e) {
      offs[e] = s; poffs[e] = p;
      int nb = (counts[e] + 127) >> 7;
      for (int i = 0; i < nb; ++i) { mb2e[mb] = e; mb2m0[mb] = i * 128; ++mb; }
      s += counts[e]; p += nb * 128;
    }
    offs[NE] = s; poffs[NE] = p;
    nmb[0] = mb;
    for (int i = mb; i < MAXMB; ++i) { mb2e[i] = 0; mb2m0[i] = 0; }
  }
}

// fused2: blocks [0,2304) = GEMM1 (128x128, BK=64, 8 waves, counted vmcnt);
//         blocks [2304,6400) = w2[e][H][D] -> w2t[e][D][H] transpose
//         (two 64x64 tiles per 512-thread block, per-half LDS regions).
__global__ __launch_bounds__(512) void fused2_kernel(
    const u16* __restrict__ xb, const u16* __restrict__ w1t,
    const float* __restrict__ b1, const int* __restrict__ counts,
    const int* __restrict__ poffs, const int* __restrict__ nmb,
    const int* __restrict__ mb2e, const int* __restrict__ mb2m0,
    const int* __restrict__ tlist, u16* __restrict__ hbuf,
    const float* __restrict__ w2, u16* __restrict__ w2t) {
  int bid = blockIdx.x;
  int tid = threadIdx.x;
  __shared__ u16 lds[32768];   // gemm: 2 stages x (A|B); transpose: 2 x 4160 region

  if (bid >= 2304) {
    // ---- w2 transpose: two 64x64 tiles ----
    int half = tid >> 8;          // 0/1
    int htid = tid & 255;
    int tileIdx = (bid - 2304) * 2 + half;
    int e = tileIdx >> 10;
    int rem = tileIdx & 1023;
    int rt = rem >> 4, ct = rem & 15;   // R=4096 (64 r-tiles), C=1024 (16 c-tiles)
    int r0 = rt * 64, c0 = ct * 64;
    u16* tile = &lds[half * 4160];      // [64][65] scalar-indexed
    int rr = htid >> 4;
    int cc = (htid & 15) * 4;
    const float* src = w2 + (size_t)e * HID * DIM + (size_t)r0 * DIM + c0;
    #pragma unroll
    for (int rd = 0; rd < 4; ++rd) {
      int r = rd * 16 + rr;
      float4 v = *(const float4*)&src[(size_t)r * DIM + cc];
      tile[r * 65 + cc + 0] = f2bf(v.x);
      tile[r * 65 + cc + 1] = f2bf(v.y);
      tile[r * 65 + cc + 2] = f2bf(v.z);
      tile[r * 65 + cc + 3] = f2bf(v.w);
    }
    __syncthreads();
    u16* dst = w2t + (size_t)e * HID * DIM + (size_t)c0 * HID + r0;
    int oc2 = htid >> 3;
    int cc8 = (htid & 7) * 8;
    #pragma unroll
    for (int rd = 0; rd < 2; ++rd) {
      int oc = rd * 32 + oc2;
      u16 tmp[8];
      #pragma unroll
      for (int jj = 0; jj < 8; ++jj) tmp[jj] = tile[(cc8 + jj) * 65 + oc];
      *(s16x8*)&dst[(size_t)oc * HID + cc8] = *(const s16x8*)tmp;
    }
    return;
  }

  // ---- GEMM1 ----
  int mb = bid >> 5;
  if (mb >= nmb[0]) return;
  int n0 = (bid & 31) << 7;
  int e = mb2e[mb];
  int m0 = mb2m0[mb];
  int ne = counts[e];

  int srow = tid >> 3;                          // 0..63
  int sch  = tid & 7;
  int kch  = ((sch ^ (srow & 7)) * 8);          // pre-swizzled source k-offset
  const u16* aSrc[2];
  const u16* bSrc[2];
  #pragma unroll
  for (int j = 0; j < 2; ++j) {
    int r = m0 + j * 64 + srow;
    int idx = r < ne ? r : ne - 1;
    aSrc[j] = xb + (size_t)(tlist[e * N_TOK + idx] >> 1) * DIM + kch;
    bSrc[j] = w1t + ((size_t)e * HID + n0 + j * 64 + srow) * DIM + kch;
  }

#define STG(kk, s) do { \
    gload16(aSrc[0] + (kk), &lds[(s) * 16384 + (0 * 64 + srow) * 64 + sch * 8]); \
    gload16(aSrc[1] + (kk), &lds[(s) * 16384 + (1 * 64 + srow) * 64 + sch * 8]); \
    gload16(bSrc[0] + (kk), &lds[(s) * 16384 + 8192 + (0 * 64 + srow) * 64 + sch * 8]); \
    gload16(bSrc[1] + (kk), &lds[(s) * 16384 + 8192 + (1 * 64 + srow) * 64 + sch * 8]); } while (0)

  int lane = tid & 63;
  int wv = tid >> 6;                 // 0..7
  int wr = (wv >> 2) * 64;           // 0 / 64
  int wc = (wv & 3) * 32;            // 0/32/64/96
  int fr = lane & 15, fq = lane >> 4;

  f32x4 acc[4][2];
  #pragma unroll
  for (int m = 0; m < 4; ++m)
    #pragma unroll
    for (int n = 0; n < 2; ++n) { f32x4 z = {0.f, 0.f, 0.f, 0.f}; acc[m][n] = z; }

  STG(0, 0);
  for (int t = 0; t < 16; ++t) {
    int cs = t & 1;
    if (t < 15) { STG((t + 1) * 64, cs ^ 1); WAITV(4); }
    else        { WAITV(0); }
    wgbar();
    {
      const u16* Ab = &lds[cs * 16384];
      const u16* Bb = &lds[cs * 16384 + 8192];
      __builtin_amdgcn_s_setprio(1);
      #pragma unroll
      for (int th = 0; th < 2; ++th) {
        s16x8 af[4], bf_[2];
        #pragma unroll
        for (int m = 0; m < 4; ++m) {
          int row = wr + m * 16 + fr;
          af[m] = *(const s16x8*)&lds[cs * 16384 + row * 64 + (((th * 4 + fq) ^ (row & 7)) * 8)];
        }
        #pragma unroll
        for (int n = 0; n < 2; ++n) {
          int row = wc + n * 16 + fr;
          bf_[n] = *(const s16x8*)&Bb[row * 64 + (((th * 4 + fq) ^ (row & 7)) * 8)];
        }
        #pragma unroll
        for (int m = 0; m < 4; ++m)
          #pragma unroll
          for (int n = 0; n < 2; ++n)
            acc[m][n] = __builtin_amdgcn_mfma_f32_16x16x32_bf16(af[m], bf_[n], acc[m][n], 0, 0, 0);
      }
      __builtin_amdgcn_s_setprio(0);
      (void)Ab;
    }
    wgbar();
  }
#undef STG

  int pbase = poffs[e] + m0;
  float bias[2];
  #pragma unroll
  for (int n = 0; n < 2; ++n) bias[n] = b1[e * HID + n0 + wc + n * 16 + fr];
  #pragma unroll
  for (int m = 0; m < 4; ++m) {
    #pragma unroll
    for (int j = 0; j < 4; ++j) {
      int row = wr + m * 16 + fq * 4 + j;
      if (m0 + row < ne) {
        u16* hr = hbuf + (size_t)(pbase + row) * HID + n0;
        #pragma unroll
        for (int n = 0; n < 2; ++n) {
          int col = wc + n * 16 + fr;
          float v = acc[m][n][j] + bias[n];
          hr[col] = f2bf(fmaxf(v, 0.f));
        }
      }
    }
  }
}

// GEMM2: y[pslot, D] = h[pslot, H] * w2t[e]^T + b2[e] -> fp32
// 128x128, BK=64, 512 threads / 8 waves, split-K x2.
__global__ __launch_bounds__(512) void gemm2_kernel(
    const u16* __restrict__ hbuf, const u16* __restrict__ w2t,
    const float* __restrict__ b2, const int* __restrict__ counts,
    const int* __restrict__ poffs, const int* __restrict__ nmb,
    const int* __restrict__ mb2e, const int* __restrict__ mb2m0,
    float* __restrict__ yb0, float* __restrict__ yb1) {
  int mb = blockIdx.y;
  if (mb >= nmb[0]) return;
  int n0 = blockIdx.x << 7;
  int z = blockIdx.z;
  int e = mb2e[mb];
  int m0 = mb2m0[mb];
  int ne = counts[e];
  int kz = z * (HID / 2);
  int tid = threadIdx.x;
  int pbase = poffs[e] + m0;

  __shared__ u16 lds[32768];

  int srow = tid >> 3;
  int sch  = tid & 7;
  int kch  = ((sch ^ (srow & 7)) * 8);
  const u16* aSrc[2];
  const u16* bSrc[2];
  #pragma unroll
  for (int j = 0; j < 2; ++j) {
    int r = m0 + j * 64 + srow;
    int idx = r < ne ? r : ne - 1;
    aSrc[j] = hbuf + (size_t)(poffs[e] + idx) * HID + kz + kch;
    bSrc[j] = w2t + ((size_t)e * DIM + n0 + j * 64 + srow) * HID + kz + kch;
  }

#define STG(kk, s) do { \
    gload16(aSrc[0] + (kk), &lds[(s) * 16384 + (0 * 64 + srow) * 64 + sch * 8]); \
    gload16(aSrc[1] + (kk), &lds[(s) * 16384 + (1 * 64 + srow) * 64 + sch * 8]); \
    gload16(bSrc[0] + (kk), &lds[(s) * 16384 + 8192 + (0 * 64 + srow) * 64 + sch * 8]); \
    gload16(bSrc[1] + (kk), &lds[(s) * 16384 + 8192 + (1 * 64 + srow) * 64 + sch * 8]); } while (0)

  int lane = tid & 63;
  int wv = tid >> 6;
  int wr = (wv >> 2) * 64;
  int wc = (wv & 3) * 32;
  int fr = lane & 15, fq = lane >> 4;

  f32x4 acc[4][2];
  #pragma unroll
  for (int m = 0; m < 4; ++m)
    #pragma unroll
    for (int n = 0; n < 2; ++n) { f32x4 zz = {0.f, 0.f, 0.f, 0.f}; acc[m][n] = zz; }

  STG(0, 0);
  for (int t = 0; t < 32; ++t) {
    int cs = t & 1;
    if (t < 31) { STG((t + 1) * 64, cs ^ 1); WAITV(4); }
    else        { WAITV(0); }
    wgbar();
    {
      const u16* Bb = &lds[cs * 16384 + 8192];
      __builtin_amdgcn_s_setprio(1);
      #pragma unroll
      for (int th = 0; th < 2; ++th) {
        s16x8 af[4], bf_[2];
        #pragma unroll
        for (int m = 0; m < 4; ++m) {
          int row = wr + m * 16 + fr;
          af[m] = *(const s16x8*)&lds[cs * 16384 + row * 64 + (((th * 4 + fq) ^ (row & 7)) * 8)];
        }
        #pragma unroll
        for (int n = 0; n < 2; ++n) {
          int row = wc + n * 16 + fr;
          bf_[n] = *(const s16x8*)&Bb[row * 64 + (((th * 4 + fq) ^ (row & 7)) * 8)];
        }
        #pragma unroll
        for (int m = 0; m < 4; ++m)
          #pragma unroll
          for (int n = 0; n < 2; ++n)
            acc[m][n] = __builtin_amdgcn_mfma_f32_16x16x32_bf16(af[m], bf_[n], acc[m][n], 0, 0, 0);
      }
      __builtin_amdgcn_s_setprio(0);
    }
    wgbar();
  }
#undef STG

  float* yb = z ? yb1 : yb0;
  float bias[2];
  #pragma unroll
  for (int n = 0; n < 2; ++n)
    bias[n] = (z == 0) ? b2[e * DIM + n0 + wc + n * 16 + fr] : 0.f;
  #pragma unroll
  for (int m = 0; m < 4; ++m) {
    #pragma unroll
    for (int j = 0; j < 4; ++j) {
      int row = wr + m * 16 + fq * 4 + j;
      if (m0 + row < ne) {
        float* yr = yb + (size_t)(pbase + row) * DIM + n0;
        #pragma unroll
        for (int n = 0; n < 2; ++n) {
          int col = wc + n * 16 + fr;
          yr[col] = acc[m][n][j] + bias[n];
        }
      }
    }
  }
}

__global__ __launch_bounds__(256) void combine_kernel(
    const int* __restrict__ eid, const int* __restrict__ pos,
    const float* __restrict__ wgt, const int* __restrict__ poffs,
    const float* __restrict__ yb0, const float* __restrict__ yb1,
    float* __restrict__ out) {
  int t = blockIdx.x;
  int e0 = eid[2 * t], e1 = eid[2 * t + 1];
  float w0 = wgt[2 * t], w1v = wgt[2 * t + 1];
  size_t g0 = (size_t)(poffs[e0] + pos[2 * t]) * DIM;
  size_t g1 = (size_t)(poffs[e1] + pos[2 * t + 1]) * DIM;
  int d = threadIdx.x * 4;
  float4 a0 = *(const float4*)&yb0[g0 + d];
  float4 a1 = *(const float4*)&yb1[g0 + d];
  float4 b0 = *(const float4*)&yb0[g1 + d];
  float4 b1v = *(const float4*)&yb1[g1 + d];
  float4 o;
  o.x = w0 * (a0.x + a1.x) + w1v * (b0.x + b1v.x);
  o.y = w0 * (a0.y + a1.y) + w1v * (b0.y + b1v.y);
  o.z = w0 * (a0.z + a1.z) + w1v * (b0.z + b1v.z);
  o.w = w0 * (a0.w + a1.w) + w1v * (b0.w + b1v.w);
  *(float4*)&out[(size_t)t * DIM + d] = o;
}

extern "C" void kernel_launch(void* const* d_in, const int* in_sizes, int n_in,
                              void* d_out, int out_size, void* d_ws, size_t ws_size,
                              hipStream_t stream) {
  const float* x  = (const float*)d_in[0];
  const float* gw = (const float*)d_in[1];
  const float* gb = (const float*)d_in[2];
  const float* w1 = (const float*)d_in[3];
  const float* b1 = (const float*)d_in[4];
  const float* w2 = (const float*)d_in[5];
  const float* b2 = (const float*)d_in[6];
  float* out = (float*)d_out;

  char* ws = (char*)d_ws;
  const size_t MB = 1ull << 20;
  // layout: [0,64)   w1t   (dead after fused2; yb0 36MB aliases here)
  //         [64,128) w2t
  //         [128,136) xb
  //         [136,208) hbuf (9216*4096*2B = 72MB)
  //         [208,244) yb1 (9216*1024*4B = 36MB)
  //         [244,...) meta
  u16*   w1t    = (u16*)(ws);
  float* yb0    = (float*)(ws);              // aliases w1t (dead before gemm2)
  u16*   w2t    = (u16*)(ws + 64 * MB);
  u16*   xb     = (u16*)(ws + 128 * MB);
  u16*   hbuf   = (u16*)(ws + 136 * MB);
  float* yb1    = (float*)(ws + 208 * MB);
  char*  meta   = ws + 244 * MB;
  int*   eid    = (int*)(meta);
  int*   pos    = (int*)(meta + 32 * 1024);
  float* wgt    = (float*)(meta + 64 * 1024);
  int*   counts = (int*)(meta + 96 * 1024);
  int*   offs   = (int*)(meta + 96 * 1024 + 256);
  int*   poffs  = (int*)(meta + 96 * 1024 + 512);
  int*   nmb    = (int*)(meta + 96 * 1024 + 768);
  int*   mb2e   = (int*)(meta + 96 * 1024 + 1024);
  int*   mb2m0  = (int*)(meta + 96 * 1024 + 2048);
  int*   tlist  = (int*)(meta + 128 * 1024);

  hipMemsetAsync(counts, 0, NE * sizeof(int), stream);
  fused1_kernel<<<9216, 256, 0, stream>>>(x, gw, gb, w1, w1t, counts, tlist,
                                          eid, pos, wgt, xb);
  scan_kernel<<<1, 64, 0, stream>>>(counts, offs, poffs, nmb, mb2e, mb2m0);
  fused2_kernel<<<6400, 512, 0, stream>>>(xb, w1t, b1, counts, poffs, nmb,
                                          mb2e, mb2m0, tlist, hbuf, w2, w2t);
  gemm2_kernel<<<dim3(8, MAXMB, 2), 512, 0, stream>>>(hbuf, w2t, b2, counts, poffs, nmb, mb2e, mb2m0, yb0, yb1);
  combine_kernel<<<N_TOK, 256, 0, stream>>>(eid, pos, wgt, poffs, yb0, yb1, out);
}